// Round 7
// baseline (110.287 us; speedup 1.0000x reference)
//
#include <hip/hip_runtime.h>
#include <math.h>

// LossLayer: dist[b,r] = ||W[b]-R[r]||2 ; pred = one_hot(argmax_r dist) ;
// loss = mean(1 + dist[b,y] - dist[b, top2-excluding-y-at-top1]), y=argmax(label[b])
//
// R7: R1..R6 pinned at 46-53 us, all pipes <=21%: with <=4 blocks/CU the
// per-chunk path (barrier + load latency vs ~600 cyc compute) dominates and
// TLP can't rise. Trade TLP for ILP:
//   grid 256 = exactly 1 block/CU, block = 4 waves, each wave owns J=4 b-rows.
//   Per chunk each wave: 16 ds_read_b128 SHARED across 4 accumulator rows ->
//   512 VALU per barrier interval (4x R6), 4 independent FMA chains = ILP.
//   W via wave-uniform scalar loads (R6: scalarizes, VGPR 32) - no LDS for W.
//   re staged with global_load_lds (only spill-free path; R2/R4 register
//   prefetch spilled 118/45 MB), PERMUTED AT STAGE TIME via the global source
//   address so compute reads are exactly R5's measured-clean geometry
//   (row stride 16 f4, rotated &15 index; R6's stride-8/&7 variant cost
//   4 cyc/instr in conflicts) while the W index stays uniform dd.
//   Two DISTINCT LDS arrays + x2-unrolled chunk loop so alias analysis can't
//   force a vmcnt(0) drain between stage(c+1) and compute(c).
#define NB 4096
#define NR 64
#define JB 4            // b-rows per wave
#define WVS 4           // waves per block
#define BBB (JB * WVS)  // 16 b-rows per block; grid = 256
#define NCH 8           // D chunks of 64 floats
#define CF4 16          // float4 per row per chunk

#define AS1 __attribute__((address_space(1)))
#define AS3 __attribute__((address_space(3)))

__device__ __forceinline__ void async_copy16(void* lds, const void* g) {
    // LDS dest = wave-uniform base + lane*16 ; global address is per-lane.
    __builtin_amdgcn_global_load_lds((const AS1 void*)g, (AS3 void*)lds, 16, 0, 0);
}

__global__ __launch_bounds__(256) void fused_loss_kernel(
    const float* __restrict__ w,
    const float* __restrict__ re,
    const float* __restrict__ label,
    float* __restrict__ out,
    float* __restrict__ ws)
{
    __shared__ float4 rlA[NR * CF4];   // 16 KB  (chunk buffer A)
    __shared__ float4 rlB[NR * CF4];   // 16 KB  (chunk buffer B)
    __shared__ float terms[WVS];

    const int tid = threadIdx.x;
    const int wv  = tid >> 6;       // wave id (uniform per wave)
    const int r   = tid & 63;       // lane = relation 0..63
    const int b0  = blockIdx.x * BBB;

    const float4* re4 = (const float4*)re;   // [64][128]

    // permuted stage of chunk c into buf: slot cs of row rho holds column
    // (cs-rho)&15, so column dd of row r sits at slot (dd+r)&15.
    // Per 16-lane group: 16 consecutive f4 of one row (256 B), rotated order.
#define STAGE(buf, c)                                                        \
    {                                                                        \
        _Pragma("unroll")                                                    \
        for (int k = 0; k < 4; k++) {                                        \
            int s0   = (wv * 4 + k) * 64;          /* wave-uniform base */   \
            int rho  = ((wv * 4 + k) * 4) + (r >> 4);                        \
            int gcol = (c) * CF4 + (((r & 15) - rho) & 15);                  \
            async_copy16(&buf[s0], re4 + rho * 128 + gcol);                  \
        }                                                                    \
    }

    STAGE(rlA, 0);

    // uniform W row pointers (readfirstlane -> provably scalar)
    const float4* wr[JB];
    #pragma unroll
    for (int j = 0; j < JB; j++) {
        int bu = __builtin_amdgcn_readfirstlane(b0 + wv * JB + j);
        wr[j] = (const float4*)(w + (size_t)bu * 512);
    }

    float4 acc[JB];
    #pragma unroll
    for (int j = 0; j < JB; j++) acc[j] = (float4){0.f, 0.f, 0.f, 0.f};

#define COMPUTE(buf, c)                                                      \
    {                                                                        \
        _Pragma("unroll")                                                    \
        for (int dd = 0; dd < CF4; dd++) {                                   \
            float4 rv = buf[r * CF4 + ((dd + r) & 15)];  /* column dd */     \
            _Pragma("unroll")                                                \
            for (int j = 0; j < JB; j++) {                                   \
                float4 a = wr[j][(c) * CF4 + dd];        /* scalar load */   \
                float dx;                                                    \
                dx = a.x - rv.x; acc[j].x = fmaf(dx, dx, acc[j].x);          \
                dx = a.y - rv.y; acc[j].y = fmaf(dx, dx, acc[j].y);          \
                dx = a.z - rv.z; acc[j].z = fmaf(dx, dx, acc[j].z);          \
                dx = a.w - rv.w; acc[j].w = fmaf(dx, dx, acc[j].w);          \
            }                                                                \
        }                                                                    \
    }

    #pragma unroll
    for (int cc = 0; cc < NCH; cc += 2) {
        __syncthreads();                    // drains own vmcnt: A-chunk ready
        if (cc + 1 < NCH) STAGE(rlB, cc + 1);
        COMPUTE(rlA, cc);
        __syncthreads();                    // B-chunk ready
        if (cc + 2 < NCH) STAGE(rlA, cc + 2);
        COMPUTE(rlB, cc + 1);
    }

    // ---- epilogue per j: top-2/argmax + label argmax + loss term ----
    float lsum = 0.0f;
    #pragma unroll
    for (int j = 0; j < JB; j++) {
        int b = b0 + wv * JB + j;
        float d = sqrtf((acc[j].x + acc[j].y) + (acc[j].z + acc[j].w));

        float m1 = d; int i1 = r; float m2 = -3.0e38f;
        #pragma unroll
        for (int mask = 1; mask <= 32; mask <<= 1) {
            float om1 = __shfl_xor(m1, mask, 64);
            int   oi1 = __shfl_xor(i1, mask, 64);
            float om2 = __shfl_xor(m2, mask, 64);
            bool ob1 = (om1 > m1) || (om1 == m1 && oi1 < i1);
            float w1 = ob1 ? om1 : m1;  int wi1 = ob1 ? oi1 : i1;
            float l1 = ob1 ? m1 : om1;          // loser's top-1 (value only)
            float c2 = ob1 ? om2 : m2;          // winner's top-2 (value only)
            m1 = w1; i1 = wi1;
            m2 = (c2 > l1) ? c2 : l1;
        }

        float lv = label[(size_t)b * 64 + r]; int ly = r;
        #pragma unroll
        for (int mask = 1; mask <= 32; mask <<= 1) {
            float ov = __shfl_xor(lv, mask, 64);
            int   oy = __shfl_xor(ly, mask, 64);
            if (ov > lv || (ov == lv && oy < ly)) { lv = ov; ly = oy; }
        }
        int y = ly;

        float plus  = __shfl(d, y, 64);       // dist[b][y]
        float minus = (i1 == y) ? m2 : m1;    // top-2 value if top-1 == y
        lsum += 1.0f + plus - minus;

        out[(size_t)b * 64 + r] = (i1 == r) ? 1.0f : 0.0f;   // pred one-hot
    }

    if (r == 0) terms[wv] = lsum;

    // ---- fused loss reduction: block partial -> device atomic -> last block
    __syncthreads();
    if (tid == 0) {
        float t = ((terms[0] + terms[1]) + (terms[2] + terms[3])) * (1.0f / NB);
        atomicAdd(ws, t);                     // ws[0] = loss accumulator (zeroed)
        __threadfence();                      // order add before counter inc
        unsigned old = atomicAdd((unsigned*)(ws + 1), 1u);   // ws[1] = counter
        if (old == (unsigned)(gridDim.x - 1)) {
            float total = atomicAdd(ws, 0.0f);   // all 256 adds visible
            out[(size_t)NB * NR] = total;
        }
    }
}

extern "C" void kernel_launch(void* const* d_in, const int* in_sizes, int n_in,
                              void* d_out, int out_size, void* d_ws, size_t ws_size,
                              hipStream_t stream) {
    const float* w   = (const float*)d_in[0];   // [4096,512]
    const float* re  = (const float*)d_in[1];   // [64,512]
    const float* lab = (const float*)d_in[2];   // [4096,64]
    float* out = (float*)d_out;                 // pred [4096,64] ++ loss [1]
    float* ws  = (float*)d_ws;                  // [0]=loss acc, [1]=done counter

    hipMemsetAsync(ws, 0, 8, stream);           // zero acc + counter (graph-safe)
    fused_loss_kernel<<<NB / BBB, 256, 0, stream>>>(w, re, lab, out, ws);
}